// Round 1
// 215.339 us; speedup vs baseline: 1.0261x; 1.0261x over previous
//
#include <hip/hip_runtime.h>

// Problem constants (B=2, T=2048, C=1024, H=16, hd=64)
#define T_SEQ 2048
#define NH    16
#define HD    64
#define CDIM  1024
#define BDIM  2

using floatx4 = __attribute__((ext_vector_type(4))) float;
using bf16x8  = __attribute__((ext_vector_type(8))) __bf16;
using half4   = __attribute__((ext_vector_type(4))) _Float16;
using half8   = __attribute__((ext_vector_type(8))) _Float16;
typedef unsigned short u16;

__device__ __forceinline__ u16 f2bf(float f) {
  unsigned int u = __float_as_uint(f);
  u += 0x7fffu + ((u >> 16) & 1u);          // RNE
  return (u16)(u >> 16);
}
__device__ __forceinline__ float bf2f(u16 h) {
  return __uint_as_float(((unsigned int)h) << 16);
}
__device__ __forceinline__ u16 f2h(float f) {
  union { _Float16 h; u16 u; } c; c.h = (_Float16)f; return c.u;
}
// packed f32x2 -> f16x2 (RTZ)
__device__ __forceinline__ unsigned pk2h(float a, float b) {
  return __builtin_bit_cast(unsigned, __builtin_amdgcn_cvt_pkrtz(a, b));
}
// async global->LDS, 16B/lane; LDS dest must be wave-uniform base + lane*16.
__device__ __forceinline__ void gld16(const void* g, const void* l) {
  __builtin_amdgcn_global_load_lds(
      (const __attribute__((address_space(1))) unsigned int*)(unsigned long long)g,
      (__attribute__((address_space(3))) unsigned int*)(unsigned int)(unsigned long long)l,
      16, 0, 0);
}

// ---------------- fused preprocessing: x cast + both weight transposes ----------------
__global__ __launch_bounds__(256) void preproc(const float* __restrict__ x,
                                               const float* __restrict__ w_qkv,
                                               const float* __restrict__ w_out,
                                               u16* __restrict__ xb,
                                               u16* __restrict__ wqT,
                                               u16* __restrict__ woT) {
  __shared__ float tile[32][33];
  int blk = blockIdx.x, tid = threadIdx.x;
  if (blk < 4096) {                         // cast x -> bf16 (4M floats, float4 per thread)
    int i = blk * 256 + tid;
    float4 v = ((const float4*)x)[i];
    ushort4 o;
    o.x = f2bf(v.x); o.y = f2bf(v.y); o.z = f2bf(v.z); o.w = f2bf(v.w);
    ((ushort4*)xb)[i] = o;
    return;
  }
  const float* W; u16* WT; int K, N, bx, by;
  if (blk < 4096 + 3072) {                  // w_qkv (1024,3072) -> wqT (3072,1024)
    int idx = blk - 4096; W = w_qkv; WT = wqT; K = 1024; N = 3072;
    bx = idx % 96; by = idx / 96;
  } else {                                  // w_out (1024,1024) -> woT
    int idx = blk - 7168; W = w_out; WT = woT; K = 1024; N = 1024;
    bx = idx & 31; by = idx >> 5;
  }
  int n0 = bx * 32, k0 = by * 32;
  int tx = tid & 31, ty = tid >> 5;         // (32,8)
#pragma unroll
  for (int i = 0; i < 32; i += 8)
    tile[ty + i][tx] = W[(size_t)(k0 + ty + i) * N + n0 + tx];
  __syncthreads();
#pragma unroll
  for (int i = 0; i < 32; i += 8)
    WT[(size_t)(n0 + ty + i) * K + k0 + tx] = f2bf(tile[tx][ty + i]);
}

// ---------------- single-bf16 GEMM (m97 structure): C(M,N) = A(M,K)*BT(N,K)^T ----------
template <bool OUT_F32>
__global__ __launch_bounds__(256) void gemm_bt(const u16* __restrict__ A,
                                               const u16* __restrict__ BT,
                                               float* __restrict__ Cf,
                                               u16* __restrict__ Cb,
                                               int M, int N, int K) {
  __shared__ u16 As[128 * 32];
  __shared__ u16 Bs[128 * 32];
  const int tid  = threadIdx.x;
  const int lane = tid & 63, wave = tid >> 6;
  const int quad = lane >> 4, l16 = lane & 15;
  const int wm = (wave & 1) * 64, wn = (wave >> 1) * 64;
  const int row0 = blockIdx.x * 128, col0 = blockIdx.y * 128;
  const int srow = tid >> 2;                       // staging row 0..63
  const int sc   = tid & 3;                        // chunk 0..3 (8 elems)
  const int sgc  = (sc ^ ((srow >> 1) & 3)) * 8;   // swizzled source chunk
  floatx4 acc[4][4] = {};
  for (int k0 = 0; k0 < K; k0 += 32) {
    __syncthreads();
    gld16(A  + (size_t)(row0 + srow     ) * K + k0 + sgc, &As[srow * 32 + sc * 8]);
    gld16(A  + (size_t)(row0 + srow + 64) * K + k0 + sgc, &As[(srow + 64) * 32 + sc * 8]);
    gld16(BT + (size_t)(col0 + srow     ) * K + k0 + sgc, &Bs[srow * 32 + sc * 8]);
    gld16(BT + (size_t)(col0 + srow + 64) * K + k0 + sgc, &Bs[(srow + 64) * 32 + sc * 8]);
    __syncthreads();
    bf16x8 af[4], bfv[4];
#pragma unroll
    for (int mt = 0; mt < 4; mt++) {
      int r = wm + mt * 16 + l16;
      af[mt] = *(const bf16x8*)&As[r * 32 + (quad ^ ((r >> 1) & 3)) * 8];
    }
#pragma unroll
    for (int nt = 0; nt < 4; nt++) {
      int r = wn + nt * 16 + l16;
      bfv[nt] = *(const bf16x8*)&Bs[r * 32 + (quad ^ ((r >> 1) & 3)) * 8];
    }
#pragma unroll
    for (int mt = 0; mt < 4; mt++)
#pragma unroll
      for (int nt = 0; nt < 4; nt++)
        acc[mt][nt] = __builtin_amdgcn_mfma_f32_16x16x32_bf16(af[mt], bfv[nt], acc[mt][nt], 0, 0, 0);
  }
  // C/D layout: col = lane&15, row = quad*4 + reg
#pragma unroll
  for (int mt = 0; mt < 4; mt++)
#pragma unroll
    for (int nt = 0; nt < 4; nt++)
#pragma unroll
      for (int r = 0; r < 4; r++) {
        int row = row0 + wm + mt * 16 + quad * 4 + r;
        int col = col0 + wn + nt * 16 + l16;
        float v = acc[mt][nt][r];
        if (OUT_F32) Cf[(size_t)row * N + col] = v;
        else         Cb[(size_t)row * N + col] = f2bf(v);
      }
}

// ---------------- fused RoPE (q,k) + V pack ----------------
__global__ __launch_bounds__(256) void rope_vpack(const u16* __restrict__ qkv,
                                                  u16* __restrict__ qf16,
                                                  u16* __restrict__ kf16,
                                                  float* __restrict__ kt_out,
                                                  float* __restrict__ vt_out,
                                                  u16* __restrict__ vtf) {
  int blk = blockIdx.x;
  if (blk < 16384) {                        // RoPE on q,k
    int gid = blk * 4 + (threadIdx.x >> 6); // (b,h,t) row index
    int d   = threadIdx.x & 63;
    int t   = gid & (T_SEQ - 1);
    int h   = (gid >> 11) & 15;
    int b   = gid >> 15;
    const u16* qrow = qkv + ((size_t)(b * T_SEQ + t)) * 3072 + h * 64;
    int i = d & 31;
    unsigned int qp = *(const unsigned int*)(qrow + 2 * i);
    unsigned int kp = *(const unsigned int*)(qrow + 1024 + 2 * i);
    float q1 = bf2f((u16)qp), q2 = bf2f((u16)(qp >> 16));
    float k1 = bf2f((u16)kp), k2 = bf2f((u16)(kp >> 16));
    float inv = expf((float)i * -0.28782313662425572f);  // 10000^(-i/32)
    float ang = (float)t * inv;
    float sn = sinf(ang), cs = cosf(ang);
    float qv = (d < 32) ? (q1 * cs - q2 * sn) : (q1 * sn + q2 * cs);
    float kv = (d < 32) ? (k1 * cs - k2 * sn) : (k1 * sn + k2 * cs);
    size_t o = (size_t)gid * 64 + d;
    qf16[o] = f2h(qv * 0.18033688011112042f);   // 0.125 * log2(e): base-2 softmax
    kf16[o] = f2h(kv);
    kt_out[o] = kv;
    return;
  }
  // V: v_t fp32 output + V^T f16 (BH,64,T)
  __shared__ float tile[64][65];
  int b2 = blk - 16384;
  int t0 = (b2 & 31) * 64;
  int bh = b2 >> 5;
  int b = bh >> 4, h = bh & 15;
  int tx = threadIdx.x & 63, ty = threadIdx.x >> 6;
#pragma unroll
  for (int i = ty; i < 64; i += 4) {
    float v = bf2f(qkv[((size_t)(b * T_SEQ + t0 + i)) * 3072 + 2048 + h * 64 + tx]);
    tile[i][tx] = v;
    vt_out[((size_t)bh * T_SEQ + t0 + i) * 64 + tx] = v;
  }
  __syncthreads();
#pragma unroll
  for (int i = ty; i < 64; i += 4)
    vtf[((size_t)bh * 64 + i) * T_SEQ + t0 + tx] = f2h(tile[tx][i]);
}

// ---------------- fused causal flash attention, S^T orientation ----------
// DUAL-STREAM PAIRED STRIPS: block (bh, j) runs strips qtA = 31-j (heavy) and
// qtB = j (light) CONCURRENTLY over one kt loop. Light strip's tile range is a
// strict prefix of the heavy strip's (nktB <= 8 < 9 <= nktA), so K/V tiles are
// staged ONCE and shared: staged tiles/block drop 17 -> 9..16, QK ak-reads and
// PV av-reads halve in the dual phase. The two independent QK->SM->PV chains
// give the scheduler MFMA||VALU overlap inside one wave (T15-style); compute
// stays uniform (17 tile-strips/block). Defer-max (T13, thr=8 in base-2) skips
// the O-rescale when the running max barely grows (P bounded by 2^8, f16-safe).
__device__ __forceinline__ void qk_dual(const u16* Ks, const half8* qfA, const half8* qfB,
                                        floatx4 (&sA)[8], floatx4 (&sB)[8],
                                        int quad, int l16) {
#pragma unroll
  for (int kc = 0; kc < 2; kc++)
#pragma unroll
    for (int st = 0; st < 8; st++) {
      int srow = st * 16 + l16;
      half8 ak = *(const half8*)&Ks[srow * 64 + (((kc * 4 + quad) ^ (srow & 7)) * 8)];
      sA[st] = __builtin_amdgcn_mfma_f32_16x16x32_f16(ak, qfA[kc], sA[st], 0, 0, 0);
      sB[st] = __builtin_amdgcn_mfma_f32_16x16x32_f16(ak, qfB[kc], sB[st], 0, 0, 0);
    }
}
__device__ __forceinline__ void qk_single(const u16* Ks, const half8* qfA,
                                          floatx4 (&sA)[8], int quad, int l16) {
#pragma unroll
  for (int kc = 0; kc < 2; kc++)
#pragma unroll
    for (int st = 0; st < 8; st++) {
      int srow = st * 16 + l16;
      half8 ak = *(const half8*)&Ks[srow * 64 + (((kc * 4 + quad) ^ (srow & 7)) * 8)];
      sA[st] = __builtin_amdgcn_mfma_f32_16x16x32_f16(ak, qfA[kc], sA[st], 0, 0, 0);
    }
}
__device__ __forceinline__ void apply_mask(floatx4 (&s)[8], int kt, int tw, int quad, int l16) {
  int tg = tw + l16;
#pragma unroll
  for (int st = 0; st < 8; st++) {
    int sg = kt * 128 + st * 16 + quad * 4;
#pragma unroll
    for (int r = 0; r < 4; r++)
      if (sg + r > tg) s[st][r] = -1e30f;
  }
}
// online softmax per t-column (base-2; scale folded into q). Defer-max: skip the
// rescale pass while max growth <= 8 (P <= 2^8, fine in f16; lrow/oacc consistent).
__device__ __forceinline__ void softmax_update(floatx4 (&s)[8], float& mrow, float& lrow,
                                               floatx4 (&oacc)[4]) {
  floatx4 vm = s[0];
#pragma unroll
  for (int st = 1; st < 8; st++) {
    vm[0] = fmaxf(vm[0], s[st][0]); vm[1] = fmaxf(vm[1], s[st][1]);
    vm[2] = fmaxf(vm[2], s[st][2]); vm[3] = fmaxf(vm[3], s[st][3]);
  }
  float mx = fmaxf(fmaxf(vm[0], vm[1]), fmaxf(vm[2], vm[3]));
  mx = fmaxf(mx, __shfl_xor(mx, 16));
  mx = fmaxf(mx, __shfl_xor(mx, 32));
  if (!__all(mx <= mrow + 8.f)) {           // rescale needed (also first tile)
    float mnew = fmaxf(mrow, mx);
    float alpha = exp2f(mrow - mnew);
    mrow = mnew;
    lrow *= alpha;
#pragma unroll
    for (int dt = 0; dt < 4; dt++) oacc[dt] *= alpha;
  }
  floatx4 vs = {0.f, 0.f, 0.f, 0.f};
#pragma unroll
  for (int st = 0; st < 8; st++) {
#pragma unroll
    for (int r = 0; r < 4; r++) s[st][r] = exp2f(s[st][r] - mrow);
    vs += s[st];
  }
  float rs = (vs[0] + vs[1]) + (vs[2] + vs[3]);
  rs += __shfl_xor(rs, 16);
  rs += __shfl_xor(rs, 32);
  lrow += rs;
}
// O^T += V^T · P^T : P^T B-frags straight from sacc registers (packed cvt).
// Dual form shares every av read between the two strips.
__device__ __forceinline__ void pv_dual(const u16* Vts, const floatx4 (&sA)[8],
                                        const floatx4 (&sB)[8], floatx4 (&oA)[4],
                                        floatx4 (&oB)[4], int qh2, int ql2, int l16) {
#pragma unroll
  for (int st = 0; st < 8; st++) {
    union { unsigned u[2]; half4 h; } pa, pb;
    pa.u[0] = pk2h(sA[st][0], sA[st][1]); pa.u[1] = pk2h(sA[st][2], sA[st][3]);
    pb.u[0] = pk2h(sB[st][0], sB[st][1]); pb.u[1] = pk2h(sB[st][2], sB[st][3]);
#pragma unroll
    for (int dt = 0; dt < 4; dt++) {
      int drow = dt * 16 + l16;
      half4 av = *(const half4*)&Vts[drow * 128 + (((st * 2 + qh2) ^ (drow & 15)) * 8) + ql2];
      oA[dt] = __builtin_amdgcn_mfma_f32_16x16x16f16(av, pa.h, oA[dt], 0, 0, 0);
      oB[dt] = __builtin_amdgcn_mfma_f32_16x16x16f16(av, pb.h, oB[dt], 0, 0, 0);
    }
  }
}
__device__ __forceinline__ void pv_single(const u16* Vts, const floatx4 (&sA)[8],
                                          floatx4 (&oA)[4], int qh2, int ql2, int l16) {
#pragma unroll
  for (int st = 0; st < 8; st++) {
    union { unsigned u[2]; half4 h; } pa;
    pa.u[0] = pk2h(sA[st][0], sA[st][1]); pa.u[1] = pk2h(sA[st][2], sA[st][3]);
#pragma unroll
    for (int dt = 0; dt < 4; dt++) {
      int drow = dt * 16 + l16;
      half4 av = *(const half4*)&Vts[drow * 128 + (((st * 2 + qh2) ^ (drow & 15)) * 8) + ql2];
      oA[dt] = __builtin_amdgcn_mfma_f32_16x16x16f16(av, pa.h, oA[dt], 0, 0, 0);
    }
  }
}
__device__ __forceinline__ void epilogue(u16* __restrict__ Ob, const floatx4 (&oacc)[4],
                                         float lrow, int b, int h, int tw, int quad, int l16) {
  int t = tw + l16;
  float invl = 1.f / lrow;
#pragma unroll
  for (int dt = 0; dt < 4; dt++) {
    int d0 = dt * 16 + quad * 4;
    ushort4 o;
    o.x = f2bf(oacc[dt][0] * invl);
    o.y = f2bf(oacc[dt][1] * invl);
    o.z = f2bf(oacc[dt][2] * invl);
    o.w = f2bf(oacc[dt][3] * invl);
    *(ushort4*)&Ob[((size_t)(b * T_SEQ) + t) * CDIM + h * HD + d0] = o;
  }
}

__global__ __launch_bounds__(256, 2) void attn_fused(const u16* __restrict__ qf16,
                                                     const u16* __restrict__ kf16,
                                                     const u16* __restrict__ vtf,
                                                     u16* __restrict__ Ob) {
  __shared__ u16 Ks[128 * 64];              // K tile (s,d) f16, chunk-swizzled
  __shared__ u16 Vts[64 * 128];             // V^T tile (d,s) f16, chunk-swizzled
  const int tid = threadIdx.x;
  const int lane = tid & 63, wave = tid >> 6;
  const int quad = lane >> 4, l16 = lane & 15;
  const int qh2 = quad >> 1, ql2 = (quad & 1) * 4;
  const int j   = blockIdx.x >> 5;          // pair index 0..15
  const int bh  = blockIdx.x & 31;
  const int b = bh >> 4, h = bh & 15;

  const int qtA = 31 - j, qtB = j;          // heavy / light strip
  const int twA = qtA * 64 + wave * 16;     // this wave's 16 t-columns, strip A
  const int twB = qtB * 64 + wave * 16;
  const int nktA = (qtA >> 1) + 1;          // 9..16 (holds A's diagonal)
  const int nktB = (qtB >> 1) + 1;          // 1..8  (strict prefix of A's range)

  // Q B-frags (16x16x32 layout) straight from global: t=tw+l16, d=kc*32+quad*8+j8
  const u16* QgA = qf16 + ((size_t)bh * T_SEQ + twA) * HD;
  const u16* QgB = qf16 + ((size_t)bh * T_SEQ + twB) * HD;
  half8 qfA[2], qfB[2];
#pragma unroll
  for (int kc = 0; kc < 2; kc++) {
    qfA[kc] = *(const half8*)&QgA[(size_t)l16 * HD + kc * 32 + quad * 8];
    qfB[kc] = *(const half8*)&QgB[(size_t)l16 * HD + kc * 32 + quad * 8];
  }

  floatx4 oaccA[4] = {}, oaccB[4] = {};     // O^T tiles [dt]
  float mA = -1e30f, lA = 0.f;
  float mB = -1e30f, lB = 0.f;

#pragma unroll 1
  for (int kt = 0; kt < nktA; kt++) {
    __syncthreads();                        // prev compute done reading Ks/Vts
    const size_t koff = ((size_t)bh * T_SEQ + kt * 128) * HD;
    const u16* Vg = vtf + (size_t)bh * HD * T_SEQ + kt * 128;
#pragma unroll
    for (int jj = 0; jj < 4; jj++) {
      int t2 = jj * 256 + tid;
      int r = t2 >> 3, c = t2 & 7;
      gld16(kf16 + koff + r * HD + (c ^ (r & 7)) * 8, &Ks[t2 * 8]);
    }
#pragma unroll
    for (int jj = 0; jj < 4; jj++) {
      int t2 = jj * 256 + tid;
      int r = t2 >> 4, c = t2 & 15;
      gld16(Vg + (size_t)r * T_SEQ + (c ^ (r & 15)) * 8, &Vts[t2 * 8]);
    }
    __syncthreads();                        // staging landed

    if (kt < nktB) {
      // dual phase: both strips consume the staged tile; two independent
      // QK->SM->PV chains for MFMA||VALU overlap, shared ak/av LDS reads.
      floatx4 sA[8] = {}, sB[8] = {};
      qk_dual(Ks, qfA, qfB, sA, sB, quad, l16);
      if (kt == nktB - 1) apply_mask(sB, kt, twB, quad, l16);
      softmax_update(sA, mA, lA, oaccA);
      softmax_update(sB, mB, lB, oaccB);
      pv_dual(Vts, sA, sB, oaccA, oaccB, qh2, ql2, l16);
    } else {
      floatx4 sA[8] = {};
      qk_single(Ks, qfA, sA, quad, l16);
      if (kt == nktA - 1) apply_mask(sA, kt, twA, quad, l16);
      softmax_update(sA, mA, lA, oaccA);
      pv_single(Vts, sA, oaccA, qh2, ql2, l16);
    }
  }
  // epilogue: O[t][d] = oacc^T / l ; write bf16 (B,T,C)
  epilogue(Ob, oaccA, lA, b, h, twA, quad, l16);
  epilogue(Ob, oaccB, lB, b, h, twB, quad, l16);
}

extern "C" void kernel_launch(void* const* d_in, const int* in_sizes, int n_in,
                              void* d_out, int out_size, void* d_ws, size_t ws_size,
                              hipStream_t stream) {
  const float* x     = (const float*)d_in[0];
  const float* w_qkv = (const float*)d_in[2];
  const float* w_out = (const float*)d_in[3];
  float* out    = (float*)d_out;                       // (B,T,C) fp32
  float* kt_out = out + (size_t)BDIM * T_SEQ * CDIM;   // (B,H,T,64) fp32
  float* vt_out = kt_out + (size_t)BDIM * T_SEQ * CDIM;

  // workspace layout (64 MB, with aliasing)
  const size_t F = (size_t)4194304;     // 4M elems = 4096x1024
  char* base = (char*)d_ws;
  u16* xb   = (u16*)base;                        // [0,8M)   dead after gemm_qkv
  u16* wqT  = xb + F;                            // [8,14M)  dead after gemm_qkv
  u16* woT  = wqT + (size_t)3145728;             // [14,16M) lives to end
  u16* qkvb = woT + (size_t)1048576;             // [16,40M) dead after rope_vpack
  u16* qf16 = qkvb + (size_t)3 * F;              // [40,48M)
  u16* kf16 = qf16 + F;                          // [48,56M)
  u16* vtf  = (u16*)base;                        // alias xb  [0,8M)
  u16* Ob   = kf16 + F;                          // [56,64M)

  preproc<<<8192, 256, 0, stream>>>(x, w_qkv, w_out, xb, wqT, woT);
  gemm_bt<false><<<dim3(32, 24), 256, 0, stream>>>(xb, wqT, (float*)nullptr, qkvb, 4096, 3072, 1024);
  rope_vpack<<<17408, 256, 0, stream>>>(qkvb, qf16, kf16, kt_out, vt_out, vtf);
  attn_fused<<<512, 256, 0, stream>>>(qf16, kf16, vtf, Ob);
  gemm_bt<true><<<dim3(32, 8), 256, 0, stream>>>(Ob, woT, out, (u16*)nullptr, 4096, 1024, 1024);
}

// Round 2
// 210.702 us; speedup vs baseline: 1.0486x; 1.0220x over previous
//
#include <hip/hip_runtime.h>

// Problem constants (B=2, T=2048, C=1024, H=16, hd=64)
#define T_SEQ 2048
#define NH    16
#define HD    64
#define CDIM  1024
#define BDIM  2

using floatx4 = __attribute__((ext_vector_type(4))) float;
using bf16x8  = __attribute__((ext_vector_type(8))) __bf16;
using half4   = __attribute__((ext_vector_type(4))) _Float16;
using half8   = __attribute__((ext_vector_type(8))) _Float16;
typedef unsigned short u16;

__device__ __forceinline__ u16 f2bf(float f) {
  unsigned int u = __float_as_uint(f);
  u += 0x7fffu + ((u >> 16) & 1u);          // RNE
  return (u16)(u >> 16);
}
__device__ __forceinline__ float bf2f(u16 h) {
  return __uint_as_float(((unsigned int)h) << 16);
}
__device__ __forceinline__ u16 f2h(float f) {
  union { _Float16 h; u16 u; } c; c.h = (_Float16)f; return c.u;
}
// packed f32x2 -> f16x2 (RTZ)
__device__ __forceinline__ unsigned pk2h(float a, float b) {
  return __builtin_bit_cast(unsigned, __builtin_amdgcn_cvt_pkrtz(a, b));
}
// async global->LDS, 16B/lane; LDS dest must be wave-uniform base + lane*16.
__device__ __forceinline__ void gld16(const void* g, const void* l) {
  __builtin_amdgcn_global_load_lds(
      (const __attribute__((address_space(1))) unsigned int*)(unsigned long long)g,
      (__attribute__((address_space(3))) unsigned int*)(unsigned int)(unsigned long long)l,
      16, 0, 0);
}

// ---------------- fused preprocessing: x cast + both weight transposes ----------------
__global__ __launch_bounds__(256) void preproc(const float* __restrict__ x,
                                               const float* __restrict__ w_qkv,
                                               const float* __restrict__ w_out,
                                               u16* __restrict__ xb,
                                               u16* __restrict__ wqT,
                                               u16* __restrict__ woT) {
  __shared__ float tile[32][33];
  int blk = blockIdx.x, tid = threadIdx.x;
  if (blk < 4096) {                         // cast x -> bf16 (4M floats, float4 per thread)
    int i = blk * 256 + tid;
    float4 v = ((const float4*)x)[i];
    ushort4 o;
    o.x = f2bf(v.x); o.y = f2bf(v.y); o.z = f2bf(v.z); o.w = f2bf(v.w);
    ((ushort4*)xb)[i] = o;
    return;
  }
  const float* W; u16* WT; int K, N, bx, by;
  if (blk < 4096 + 3072) {                  // w_qkv (1024,3072) -> wqT (3072,1024)
    int idx = blk - 4096; W = w_qkv; WT = wqT; K = 1024; N = 3072;
    bx = idx % 96; by = idx / 96;
  } else {                                  // w_out (1024,1024) -> woT
    int idx = blk - 7168; W = w_out; WT = woT; K = 1024; N = 1024;
    bx = idx & 31; by = idx >> 5;
  }
  int n0 = bx * 32, k0 = by * 32;
  int tx = tid & 31, ty = tid >> 5;         // (32,8)
#pragma unroll
  for (int i = 0; i < 32; i += 8)
    tile[ty + i][tx] = W[(size_t)(k0 + ty + i) * N + n0 + tx];
  __syncthreads();
#pragma unroll
  for (int i = 0; i < 32; i += 8)
    WT[(size_t)(n0 + ty + i) * K + k0 + tx] = f2bf(tile[tx][ty + i]);
}

// ---------------- single-bf16 GEMM: C(M,N) = A(M,K)*BT(N,K)^T ----------
// 2-phase double-buffered LDS with COUNTED vmcnt (T3/T4 minimum form): stage
// tile ki+1 into buf^1 while MFMAs consume buf, wait vmcnt(4) (next tile's 4
// loads stay in flight across the barrier), raw s_barrier (no lgkm/vm drain).
// This removes the vmcnt(0) staging drain — critical for gemm_out (1 block/CU,
// zero implicit wave overlap).
template <bool OUT_F32>
__global__ __launch_bounds__(256) void gemm_bt(const u16* __restrict__ A,
                                               const u16* __restrict__ BT,
                                               float* __restrict__ Cf,
                                               u16* __restrict__ Cb,
                                               int M, int N, int K) {
  __shared__ u16 As[2][128 * 32];
  __shared__ u16 Bs[2][128 * 32];
  const int tid  = threadIdx.x;
  const int lane = tid & 63, wave = tid >> 6;
  const int quad = lane >> 4, l16 = lane & 15;
  const int wm = (wave & 1) * 64, wn = (wave >> 1) * 64;
  const int row0 = blockIdx.x * 128, col0 = blockIdx.y * 128;
  const int srow = tid >> 2;                       // staging row 0..63
  const int sc   = tid & 3;                        // chunk 0..3 (8 elems)
  const int sgc  = (sc ^ ((srow >> 1) & 3)) * 8;   // swizzled source chunk
  floatx4 acc[4][4] = {};

  auto stage = [&](int buf, int k0) {
    gld16(A  + (size_t)(row0 + srow     ) * K + k0 + sgc, &As[buf][srow * 32 + sc * 8]);
    gld16(A  + (size_t)(row0 + srow + 64) * K + k0 + sgc, &As[buf][(srow + 64) * 32 + sc * 8]);
    gld16(BT + (size_t)(col0 + srow     ) * K + k0 + sgc, &Bs[buf][srow * 32 + sc * 8]);
    gld16(BT + (size_t)(col0 + srow + 64) * K + k0 + sgc, &Bs[buf][(srow + 64) * 32 + sc * 8]);
  };

  const int nk = K >> 5;
  stage(0, 0);
  for (int ki = 0; ki < nk; ki++) {
    const int cur = ki & 1;
    __builtin_amdgcn_s_barrier();           // all waves done reading buf cur^1
    int kn = ki + 1 < nk ? ki + 1 : nk - 1; // clamp: last iter re-stages (harmless)
    stage(cur ^ 1, kn << 5);
    asm volatile("s_waitcnt vmcnt(4)" ::: "memory");  // tile ki landed; 4 in flight
    __builtin_amdgcn_s_barrier();           // whole tile ki visible to all waves
    bf16x8 af[4], bfv[4];
#pragma unroll
    for (int mt = 0; mt < 4; mt++) {
      int r = wm + mt * 16 + l16;
      af[mt] = *(const bf16x8*)&As[cur][r * 32 + (quad ^ ((r >> 1) & 3)) * 8];
    }
#pragma unroll
    for (int nt = 0; nt < 4; nt++) {
      int r = wn + nt * 16 + l16;
      bfv[nt] = *(const bf16x8*)&Bs[cur][r * 32 + (quad ^ ((r >> 1) & 3)) * 8];
    }
#pragma unroll
    for (int mt = 0; mt < 4; mt++)
#pragma unroll
      for (int nt = 0; nt < 4; nt++)
        acc[mt][nt] = __builtin_amdgcn_mfma_f32_16x16x32_bf16(af[mt], bfv[nt], acc[mt][nt], 0, 0, 0);
  }
  asm volatile("s_waitcnt vmcnt(0)" ::: "memory");  // drain tail stage before exit
  // C/D layout: col = lane&15, row = quad*4 + reg
#pragma unroll
  for (int mt = 0; mt < 4; mt++)
#pragma unroll
    for (int nt = 0; nt < 4; nt++)
#pragma unroll
      for (int r = 0; r < 4; r++) {
        int row = row0 + wm + mt * 16 + quad * 4 + r;
        int col = col0 + wn + nt * 16 + l16;
        float v = acc[mt][nt][r];
        if (OUT_F32) Cf[(size_t)row * N + col] = v;
        else         Cb[(size_t)row * N + col] = f2bf(v);
      }
}

// ---------------- fused RoPE (q,k) + V pack ----------------
__global__ __launch_bounds__(256) void rope_vpack(const u16* __restrict__ qkv,
                                                  u16* __restrict__ qf16,
                                                  u16* __restrict__ kf16,
                                                  float* __restrict__ kt_out,
                                                  float* __restrict__ vt_out,
                                                  u16* __restrict__ vtf) {
  int blk = blockIdx.x;
  if (blk < 16384) {                        // RoPE on q,k
    int gid = blk * 4 + (threadIdx.x >> 6); // (b,h,t) row index
    int d   = threadIdx.x & 63;
    int t   = gid & (T_SEQ - 1);
    int h   = (gid >> 11) & 15;
    int b   = gid >> 15;
    const u16* qrow = qkv + ((size_t)(b * T_SEQ + t)) * 3072 + h * 64;
    int i = d & 31;
    unsigned int qp = *(const unsigned int*)(qrow + 2 * i);
    unsigned int kp = *(const unsigned int*)(qrow + 1024 + 2 * i);
    float q1 = bf2f((u16)qp), q2 = bf2f((u16)(qp >> 16));
    float k1 = bf2f((u16)kp), k2 = bf2f((u16)(kp >> 16));
    float inv = expf((float)i * -0.28782313662425572f);  // 10000^(-i/32)
    float ang = (float)t * inv;
    float sn = sinf(ang), cs = cosf(ang);
    float qv = (d < 32) ? (q1 * cs - q2 * sn) : (q1 * sn + q2 * cs);
    float kv = (d < 32) ? (k1 * cs - k2 * sn) : (k1 * sn + k2 * cs);
    size_t o = (size_t)gid * 64 + d;
    qf16[o] = f2h(qv * 0.18033688011112042f);   // 0.125 * log2(e): base-2 softmax
    kf16[o] = f2h(kv);
    kt_out[o] = kv;
    return;
  }
  // V: v_t fp32 output + V^T f16 (BH,64,T)
  __shared__ float tile[64][65];
  int b2 = blk - 16384;
  int t0 = (b2 & 31) * 64;
  int bh = b2 >> 5;
  int b = bh >> 4, h = bh & 15;
  int tx = threadIdx.x & 63, ty = threadIdx.x >> 6;
#pragma unroll
  for (int i = ty; i < 64; i += 4) {
    float v = bf2f(qkv[((size_t)(b * T_SEQ + t0 + i)) * 3072 + 2048 + h * 64 + tx]);
    tile[i][tx] = v;
    vt_out[((size_t)bh * T_SEQ + t0 + i) * 64 + tx] = v;
  }
  __syncthreads();
#pragma unroll
  for (int i = ty; i < 64; i += 4)
    vtf[((size_t)bh * 64 + i) * T_SEQ + t0 + tx] = f2h(tile[tx][i]);
}

// ---------------- fused causal flash attention, S^T orientation ----------
// DUAL-STREAM PAIRED STRIPS (R1) + 2-phase double-buffered K/V staging with
// counted vmcnt(8) and raw barriers (R2): the next tile's 8 global_load_lds
// stay in flight across the barrier while QK/SM/PV run on the current tile —
// the vmcnt(0) staging drain (the ~30% no-issue gap in R1's counters) is gone.
// T5 s_setprio(1) wraps the MFMA clusters (attn-positive per m191).
__device__ __forceinline__ void qk_dual(const u16* Ks, const half8* qfA, const half8* qfB,
                                        floatx4 (&sA)[8], floatx4 (&sB)[8],
                                        int quad, int l16) {
#pragma unroll
  for (int kc = 0; kc < 2; kc++)
#pragma unroll
    for (int st = 0; st < 8; st++) {
      int srow = st * 16 + l16;
      half8 ak = *(const half8*)&Ks[srow * 64 + (((kc * 4 + quad) ^ (srow & 7)) * 8)];
      sA[st] = __builtin_amdgcn_mfma_f32_16x16x32_f16(ak, qfA[kc], sA[st], 0, 0, 0);
      sB[st] = __builtin_amdgcn_mfma_f32_16x16x32_f16(ak, qfB[kc], sB[st], 0, 0, 0);
    }
}
__device__ __forceinline__ void qk_single(const u16* Ks, const half8* qfA,
                                          floatx4 (&sA)[8], int quad, int l16) {
#pragma unroll
  for (int kc = 0; kc < 2; kc++)
#pragma unroll
    for (int st = 0; st < 8; st++) {
      int srow = st * 16 + l16;
      half8 ak = *(const half8*)&Ks[srow * 64 + (((kc * 4 + quad) ^ (srow & 7)) * 8)];
      sA[st] = __builtin_amdgcn_mfma_f32_16x16x32_f16(ak, qfA[kc], sA[st], 0, 0, 0);
    }
}
__device__ __forceinline__ void apply_mask(floatx4 (&s)[8], int kt, int tw, int quad, int l16) {
  int tg = tw + l16;
#pragma unroll
  for (int st = 0; st < 8; st++) {
    int sg = kt * 128 + st * 16 + quad * 4;
#pragma unroll
    for (int r = 0; r < 4; r++)
      if (sg + r > tg) s[st][r] = -1e30f;
  }
}
// online softmax per t-column (base-2; scale folded into q). Defer-max: skip the
// rescale pass while max growth <= 8 (P <= 2^8, fine in f16; lrow/oacc consistent).
__device__ __forceinline__ void softmax_update(floatx4 (&s)[8], float& mrow, float& lrow,
                                               floatx4 (&oacc)[4]) {
  floatx4 vm = s[0];
#pragma unroll
  for (int st = 1; st < 8; st++) {
    vm[0] = fmaxf(vm[0], s[st][0]); vm[1] = fmaxf(vm[1], s[st][1]);
    vm[2] = fmaxf(vm[2], s[st][2]); vm[3] = fmaxf(vm[3], s[st][3]);
  }
  float mx = fmaxf(fmaxf(vm[0], vm[1]), fmaxf(vm[2], vm[3]));
  mx = fmaxf(mx, __shfl_xor(mx, 16));
  mx = fmaxf(mx, __shfl_xor(mx, 32));
  if (!__all(mx <= mrow + 8.f)) {           // rescale needed (also first tile)
    float mnew = fmaxf(mrow, mx);
    float alpha = exp2f(mrow - mnew);
    mrow = mnew;
    lrow *= alpha;
#pragma unroll
    for (int dt = 0; dt < 4; dt++) oacc[dt] *= alpha;
  }
  floatx4 vs = {0.f, 0.f, 0.f, 0.f};
#pragma unroll
  for (int st = 0; st < 8; st++) {
#pragma unroll
    for (int r = 0; r < 4; r++) s[st][r] = exp2f(s[st][r] - mrow);
    vs += s[st];
  }
  float rs = (vs[0] + vs[1]) + (vs[2] + vs[3]);
  rs += __shfl_xor(rs, 16);
  rs += __shfl_xor(rs, 32);
  lrow += rs;
}
// O^T += V^T · P^T : P^T B-frags straight from sacc registers (packed cvt).
// Dual form shares every av read between the two strips.
__device__ __forceinline__ void pv_dual(const u16* Vts, const floatx4 (&sA)[8],
                                        const floatx4 (&sB)[8], floatx4 (&oA)[4],
                                        floatx4 (&oB)[4], int qh2, int ql2, int l16) {
#pragma unroll
  for (int st = 0; st < 8; st++) {
    union { unsigned u[2]; half4 h; } pa, pb;
    pa.u[0] = pk2h(sA[st][0], sA[st][1]); pa.u[1] = pk2h(sA[st][2], sA[st][3]);
    pb.u[0] = pk2h(sB[st][0], sB[st][1]); pb.u[1] = pk2h(sB[st][2], sB[st][3]);
#pragma unroll
    for (int dt = 0; dt < 4; dt++) {
      int drow = dt * 16 + l16;
      half4 av = *(const half4*)&Vts[drow * 128 + (((st * 2 + qh2) ^ (drow & 15)) * 8) + ql2];
      oA[dt] = __builtin_amdgcn_mfma_f32_16x16x16f16(av, pa.h, oA[dt], 0, 0, 0);
      oB[dt] = __builtin_amdgcn_mfma_f32_16x16x16f16(av, pb.h, oB[dt], 0, 0, 0);
    }
  }
}
__device__ __forceinline__ void pv_single(const u16* Vts, const floatx4 (&sA)[8],
                                          floatx4 (&oA)[4], int qh2, int ql2, int l16) {
#pragma unroll
  for (int st = 0; st < 8; st++) {
    union { unsigned u[2]; half4 h; } pa;
    pa.u[0] = pk2h(sA[st][0], sA[st][1]); pa.u[1] = pk2h(sA[st][2], sA[st][3]);
#pragma unroll
    for (int dt = 0; dt < 4; dt++) {
      int drow = dt * 16 + l16;
      half4 av = *(const half4*)&Vts[drow * 128 + (((st * 2 + qh2) ^ (drow & 15)) * 8) + ql2];
      oA[dt] = __builtin_amdgcn_mfma_f32_16x16x16f16(av, pa.h, oA[dt], 0, 0, 0);
    }
  }
}
__device__ __forceinline__ void epilogue(u16* __restrict__ Ob, const floatx4 (&oacc)[4],
                                         float lrow, int b, int h, int tw, int quad, int l16) {
  int t = tw + l16;
  float invl = 1.f / lrow;
#pragma unroll
  for (int dt = 0; dt < 4; dt++) {
    int d0 = dt * 16 + quad * 4;
    ushort4 o;
    o.x = f2bf(oacc[dt][0] * invl);
    o.y = f2bf(oacc[dt][1] * invl);
    o.z = f2bf(oacc[dt][2] * invl);
    o.w = f2bf(oacc[dt][3] * invl);
    *(ushort4*)&Ob[((size_t)(b * T_SEQ) + t) * CDIM + h * HD + d0] = o;
  }
}

__global__ __launch_bounds__(256, 2) void attn_fused(const u16* __restrict__ qf16,
                                                     const u16* __restrict__ kf16,
                                                     const u16* __restrict__ vtf,
                                                     u16* __restrict__ Ob) {
  __shared__ u16 Ks[2][128 * 64];           // K tile (s,d) f16, chunk-swizzled, dbuf
  __shared__ u16 Vts[2][64 * 128];          // V^T tile (d,s) f16, chunk-swizzled, dbuf
  const int tid = threadIdx.x;
  const int lane = tid & 63, wave = tid >> 6;
  const int quad = lane >> 4, l16 = lane & 15;
  const int qh2 = quad >> 1, ql2 = (quad & 1) * 4;
  const int j   = blockIdx.x >> 5;          // pair index 0..15
  const int bh  = blockIdx.x & 31;
  const int b = bh >> 4, h = bh & 15;

  const int qtA = 31 - j, qtB = j;          // heavy / light strip
  const int twA = qtA * 64 + wave * 16;     // this wave's 16 t-columns, strip A
  const int twB = qtB * 64 + wave * 16;
  const int nktA = (qtA >> 1) + 1;          // 9..16 (holds A's diagonal)
  const int nktB = (qtB >> 1) + 1;          // 1..8  (strict prefix of A's range)

  // Q B-frags (16x16x32 layout) straight from global: t=tw+l16, d=kc*32+quad*8+j8
  const u16* QgA = qf16 + ((size_t)bh * T_SEQ + twA) * HD;
  const u16* QgB = qf16 + ((size_t)bh * T_SEQ + twB) * HD;
  half8 qfA[2], qfB[2];
#pragma unroll
  for (int kc = 0; kc < 2; kc++) {
    qfA[kc] = *(const half8*)&QgA[(size_t)l16 * HD + kc * 32 + quad * 8];
    qfB[kc] = *(const half8*)&QgB[(size_t)l16 * HD + kc * 32 + quad * 8];
  }

  auto stage = [&](int buf, int kt) {
    const size_t koff = ((size_t)bh * T_SEQ + kt * 128) * HD;
    const u16* Vg = vtf + (size_t)bh * HD * T_SEQ + kt * 128;
    u16* Kd = &Ks[buf][0];
    u16* Vd = &Vts[buf][0];
#pragma unroll
    for (int jj = 0; jj < 4; jj++) {
      int t2 = jj * 256 + tid;
      int r = t2 >> 3, c = t2 & 7;
      gld16(kf16 + koff + r * HD + (c ^ (r & 7)) * 8, Kd + t2 * 8);
    }
#pragma unroll
    for (int jj = 0; jj < 4; jj++) {
      int t2 = jj * 256 + tid;
      int r = t2 >> 4, c = t2 & 15;
      gld16(Vg + (size_t)r * T_SEQ + (c ^ (r & 15)) * 8, Vd + t2 * 8);
    }
  };

  floatx4 oaccA[4] = {}, oaccB[4] = {};     // O^T tiles [dt]
  float mA = -1e30f, lA = 0.f;
  float mB = -1e30f, lB = 0.f;

  stage(0, 0);                              // prologue: tile 0 in flight
#pragma unroll 1
  for (int kt = 0; kt < nktA; kt++) {
    const int cur = kt & 1;
    __builtin_amdgcn_s_barrier();           // all waves done reading buf cur^1
    int ktn = kt + 1 < nktA ? kt + 1 : nktA - 1;  // clamp: last iter re-stages
    stage(cur ^ 1, ktn);
    asm volatile("s_waitcnt vmcnt(8)" ::: "memory");  // tile kt landed; 8 in flight
    __builtin_amdgcn_s_barrier();           // whole tile kt visible to all waves
    const u16* Kc = &Ks[cur][0];
    const u16* Vc = &Vts[cur][0];

    if (kt < nktB) {
      // dual phase: both strips consume the staged tile; two independent
      // QK->SM->PV chains for MFMA||VALU overlap, shared ak/av LDS reads.
      floatx4 sA[8] = {}, sB[8] = {};
      __builtin_amdgcn_s_setprio(1);
      qk_dual(Kc, qfA, qfB, sA, sB, quad, l16);
      __builtin_amdgcn_s_setprio(0);
      if (kt == nktB - 1) apply_mask(sB, kt, twB, quad, l16);
      softmax_update(sA, mA, lA, oaccA);
      softmax_update(sB, mB, lB, oaccB);
      __builtin_amdgcn_s_setprio(1);
      pv_dual(Vc, sA, sB, oaccA, oaccB, qh2, ql2, l16);
      __builtin_amdgcn_s_setprio(0);
    } else {
      floatx4 sA[8] = {};
      __builtin_amdgcn_s_setprio(1);
      qk_single(Kc, qfA, sA, quad, l16);
      __builtin_amdgcn_s_setprio(0);
      if (kt == nktA - 1) apply_mask(sA, kt, twA, quad, l16);
      softmax_update(sA, mA, lA, oaccA);
      __builtin_amdgcn_s_setprio(1);
      pv_single(Vc, sA, oaccA, qh2, ql2, l16);
      __builtin_amdgcn_s_setprio(0);
    }
  }
  asm volatile("s_waitcnt vmcnt(0)" ::: "memory");  // drain tail stage before exit
  // epilogue: O[t][d] = oacc^T / l ; write bf16 (B,T,C)
  epilogue(Ob, oaccA, lA, b, h, twA, quad, l16);
  epilogue(Ob, oaccB, lB, b, h, twB, quad, l16);
}

extern "C" void kernel_launch(void* const* d_in, const int* in_sizes, int n_in,
                              void* d_out, int out_size, void* d_ws, size_t ws_size,
                              hipStream_t stream) {
  const float* x     = (const float*)d_in[0];
  const float* w_qkv = (const float*)d_in[2];
  const float* w_out = (const float*)d_in[3];
  float* out    = (float*)d_out;                       // (B,T,C) fp32
  float* kt_out = out + (size_t)BDIM * T_SEQ * CDIM;   // (B,H,T,64) fp32
  float* vt_out = kt_out + (size_t)BDIM * T_SEQ * CDIM;

  // workspace layout (64 MB, with aliasing)
  const size_t F = (size_t)4194304;     // 4M elems = 4096x1024
  char* base = (char*)d_ws;
  u16* xb   = (u16*)base;                        // [0,8M)   dead after gemm_qkv
  u16* wqT  = xb + F;                            // [8,14M)  dead after gemm_qkv
  u16* woT  = wqT + (size_t)3145728;             // [14,16M) lives to end
  u16* qkvb = woT + (size_t)1048576;             // [16,40M) dead after rope_vpack
  u16* qf16 = qkvb + (size_t)3 * F;              // [40,48M)
  u16* kf16 = qf16 + F;                          // [48,56M)
  u16* vtf  = (u16*)base;                        // alias xb  [0,8M)
  u16* Ob   = kf16 + F;                          // [56,64M)

  preproc<<<8192, 256, 0, stream>>>(x, w_qkv, w_out, xb, wqT, woT);
  gemm_bt<false><<<dim3(32, 24), 256, 0, stream>>>(xb, wqT, (float*)nullptr, qkvb, 4096, 3072, 1024);
  rope_vpack<<<17408, 256, 0, stream>>>(qkvb, qf16, kf16, kt_out, vt_out, vtf);
  attn_fused<<<512, 256, 0, stream>>>(qf16, kf16, vtf, Ob);
  gemm_bt<true><<<dim3(32, 8), 256, 0, stream>>>(Ob, woT, out, (u16*)nullptr, 4096, 1024, 1024);
}

// Round 3
// 209.249 us; speedup vs baseline: 1.0559x; 1.0069x over previous
//
#include <hip/hip_runtime.h>

// Problem constants (B=2, T=2048, C=1024, H=16, hd=64)
#define T_SEQ 2048
#define NH    16
#define HD    64
#define CDIM  1024
#define BDIM  2

using floatx4 = __attribute__((ext_vector_type(4))) float;
using bf16x8  = __attribute__((ext_vector_type(8))) __bf16;
using half4   = __attribute__((ext_vector_type(4))) _Float16;
using half8   = __attribute__((ext_vector_type(8))) _Float16;
typedef unsigned short u16;

__device__ __forceinline__ u16 f2bf(float f) {
  unsigned int u = __float_as_uint(f);
  u += 0x7fffu + ((u >> 16) & 1u);          // RNE
  return (u16)(u >> 16);
}
__device__ __forceinline__ float bf2f(u16 h) {
  return __uint_as_float(((unsigned int)h) << 16);
}
__device__ __forceinline__ u16 f2h(float f) {
  union { _Float16 h; u16 u; } c; c.h = (_Float16)f; return c.u;
}
// packed f32x2 -> f16x2 (RTZ)
__device__ __forceinline__ unsigned pk2h(float a, float b) {
  return __builtin_bit_cast(unsigned, __builtin_amdgcn_cvt_pkrtz(a, b));
}
// async global->LDS, 16B/lane; LDS dest must be wave-uniform base + lane*16.
__device__ __forceinline__ void gld16(const void* g, const void* l) {
  __builtin_amdgcn_global_load_lds(
      (const __attribute__((address_space(1))) unsigned int*)(unsigned long long)g,
      (__attribute__((address_space(3))) unsigned int*)(unsigned int)(unsigned long long)l,
      16, 0, 0);
}

// ---------------- fused preprocessing: x cast + both weight transposes ----------------
__global__ __launch_bounds__(256) void preproc(const float* __restrict__ x,
                                               const float* __restrict__ w_qkv,
                                               const float* __restrict__ w_out,
                                               u16* __restrict__ xb,
                                               u16* __restrict__ wqT,
                                               u16* __restrict__ woT) {
  __shared__ float tile[32][33];
  int blk = blockIdx.x, tid = threadIdx.x;
  if (blk < 4096) {                         // cast x -> bf16 (4M floats, float4 per thread)
    int i = blk * 256 + tid;
    float4 v = ((const float4*)x)[i];
    ushort4 o;
    o.x = f2bf(v.x); o.y = f2bf(v.y); o.z = f2bf(v.z); o.w = f2bf(v.w);
    ((ushort4*)xb)[i] = o;
    return;
  }
  const float* W; u16* WT; int K, N, bx, by;
  if (blk < 4096 + 3072) {                  // w_qkv (1024,3072) -> wqT (3072,1024)
    int idx = blk - 4096; W = w_qkv; WT = wqT; K = 1024; N = 3072;
    bx = idx % 96; by = idx / 96;
  } else {                                  // w_out (1024,1024) -> woT
    int idx = blk - 7168; W = w_out; WT = woT; K = 1024; N = 1024;
    bx = idx & 31; by = idx >> 5;
  }
  int n0 = bx * 32, k0 = by * 32;
  int tx = tid & 31, ty = tid >> 5;         // (32,8)
#pragma unroll
  for (int i = 0; i < 32; i += 8)
    tile[ty + i][tx] = W[(size_t)(k0 + ty + i) * N + n0 + tx];
  __syncthreads();
#pragma unroll
  for (int i = 0; i < 32; i += 8)
    WT[(size_t)(n0 + ty + i) * K + k0 + tx] = f2bf(tile[tx][ty + i]);
}

// ---------------- single-bf16 GEMM: C(M,N) = A(M,K)*BT(N,K)^T ----------
// 2-phase double-buffered LDS with COUNTED vmcnt (T3/T4 minimum form): stage
// tile ki+1 into buf^1 while MFMAs consume buf, wait vmcnt(4) (next tile's 4
// loads stay in flight across the barrier), raw s_barrier (no lgkm/vm drain).
// Proven +20us total in R2 (gemm_out at 1 block/CU had zero implicit overlap).
template <bool OUT_F32>
__global__ __launch_bounds__(256) void gemm_bt(const u16* __restrict__ A,
                                               const u16* __restrict__ BT,
                                               float* __restrict__ Cf,
                                               u16* __restrict__ Cb,
                                               int M, int N, int K) {
  __shared__ u16 As[2][128 * 32];
  __shared__ u16 Bs[2][128 * 32];
  const int tid  = threadIdx.x;
  const int lane = tid & 63, wave = tid >> 6;
  const int quad = lane >> 4, l16 = lane & 15;
  const int wm = (wave & 1) * 64, wn = (wave >> 1) * 64;
  const int row0 = blockIdx.x * 128, col0 = blockIdx.y * 128;
  const int srow = tid >> 2;                       // staging row 0..63
  const int sc   = tid & 3;                        // chunk 0..3 (8 elems)
  const int sgc  = (sc ^ ((srow >> 1) & 3)) * 8;   // swizzled source chunk
  floatx4 acc[4][4] = {};

  auto stage = [&](int buf, int k0) {
    gld16(A  + (size_t)(row0 + srow     ) * K + k0 + sgc, &As[buf][srow * 32 + sc * 8]);
    gld16(A  + (size_t)(row0 + srow + 64) * K + k0 + sgc, &As[buf][(srow + 64) * 32 + sc * 8]);
    gld16(BT + (size_t)(col0 + srow     ) * K + k0 + sgc, &Bs[buf][srow * 32 + sc * 8]);
    gld16(BT + (size_t)(col0 + srow + 64) * K + k0 + sgc, &Bs[buf][(srow + 64) * 32 + sc * 8]);
  };

  const int nk = K >> 5;
  stage(0, 0);
  for (int ki = 0; ki < nk; ki++) {
    const int cur = ki & 1;
    __builtin_amdgcn_s_barrier();           // all waves done reading buf cur^1
    int kn = ki + 1 < nk ? ki + 1 : nk - 1; // clamp: last iter re-stages (harmless)
    stage(cur ^ 1, kn << 5);
    asm volatile("s_waitcnt vmcnt(4)" ::: "memory");  // tile ki landed; 4 in flight
    __builtin_amdgcn_s_barrier();           // whole tile ki visible to all waves
    bf16x8 af[4], bfv[4];
#pragma unroll
    for (int mt = 0; mt < 4; mt++) {
      int r = wm + mt * 16 + l16;
      af[mt] = *(const bf16x8*)&As[cur][r * 32 + (quad ^ ((r >> 1) & 3)) * 8];
    }
#pragma unroll
    for (int nt = 0; nt < 4; nt++) {
      int r = wn + nt * 16 + l16;
      bfv[nt] = *(const bf16x8*)&Bs[cur][r * 32 + (quad ^ ((r >> 1) & 3)) * 8];
    }
#pragma unroll
    for (int mt = 0; mt < 4; mt++)
#pragma unroll
      for (int nt = 0; nt < 4; nt++)
        acc[mt][nt] = __builtin_amdgcn_mfma_f32_16x16x32_bf16(af[mt], bfv[nt], acc[mt][nt], 0, 0, 0);
  }
  asm volatile("s_waitcnt vmcnt(0)" ::: "memory");  // drain tail stage before exit
  // C/D layout: col = lane&15, row = quad*4 + reg
#pragma unroll
  for (int mt = 0; mt < 4; mt++)
#pragma unroll
    for (int nt = 0; nt < 4; nt++)
#pragma unroll
      for (int r = 0; r < 4; r++) {
        int row = row0 + wm + mt * 16 + quad * 4 + r;
        int col = col0 + wn + nt * 16 + l16;
        float v = acc[mt][nt][r];
        if (OUT_F32) Cf[(size_t)row * N + col] = v;
        else         Cb[(size_t)row * N + col] = f2bf(v);
      }
}

// ---------------- fused RoPE (q,k) + V pack ----------------
__global__ __launch_bounds__(256) void rope_vpack(const u16* __restrict__ qkv,
                                                  u16* __restrict__ qf16,
                                                  u16* __restrict__ kf16,
                                                  float* __restrict__ kt_out,
                                                  float* __restrict__ vt_out,
                                                  u16* __restrict__ vtf) {
  int blk = blockIdx.x;
  if (blk < 16384) {                        // RoPE on q,k
    int gid = blk * 4 + (threadIdx.x >> 6); // (b,h,t) row index
    int d   = threadIdx.x & 63;
    int t   = gid & (T_SEQ - 1);
    int h   = (gid >> 11) & 15;
    int b   = gid >> 15;
    const u16* qrow = qkv + ((size_t)(b * T_SEQ + t)) * 3072 + h * 64;
    int i = d & 31;
    unsigned int qp = *(const unsigned int*)(qrow + 2 * i);
    unsigned int kp = *(const unsigned int*)(qrow + 1024 + 2 * i);
    float q1 = bf2f((u16)qp), q2 = bf2f((u16)(qp >> 16));
    float k1 = bf2f((u16)kp), k2 = bf2f((u16)(kp >> 16));
    float inv = expf((float)i * -0.28782313662425572f);  // 10000^(-i/32)
    float ang = (float)t * inv;
    float sn = sinf(ang), cs = cosf(ang);
    float qv = (d < 32) ? (q1 * cs - q2 * sn) : (q1 * sn + q2 * cs);
    float kv = (d < 32) ? (k1 * cs - k2 * sn) : (k1 * sn + k2 * cs);
    size_t o = (size_t)gid * 64 + d;
    qf16[o] = f2h(qv * 0.18033688011112042f);   // 0.125 * log2(e): base-2 softmax
    kf16[o] = f2h(kv);
    kt_out[o] = kv;
    return;
  }
  // V: v_t fp32 output + V^T f16 (BH,64,T)
  __shared__ float tile[64][65];
  int b2 = blk - 16384;
  int t0 = (b2 & 31) * 64;
  int bh = b2 >> 5;
  int b = bh >> 4, h = bh & 15;
  int tx = threadIdx.x & 63, ty = threadIdx.x >> 6;
#pragma unroll
  for (int i = ty; i < 64; i += 4) {
    float v = bf2f(qkv[((size_t)(b * T_SEQ + t0 + i)) * 3072 + 2048 + h * 64 + tx]);
    tile[i][tx] = v;
    vt_out[((size_t)bh * T_SEQ + t0 + i) * 64 + tx] = v;
  }
  __syncthreads();
#pragma unroll
  for (int i = ty; i < 64; i += 4)
    vtf[((size_t)bh * 64 + i) * T_SEQ + t0 + tx] = f2h(tile[tx][i]);
}

// ---------------- fused causal flash attention, S^T orientation ----------
// DUAL-STREAM PAIRED STRIPS (R1) + 2-phase double-buffered K/V staging with
// counted vmcnt(8) and raw barriers (R2), setprio REMOVED (R3): R2's A/B
// showed setprio in this barrier-coupled 4-wave structure causes priority
// inversion (prio-0 softmax waves starve while prio-1 MFMA waves run, then
// everyone waits at the barrier) — m190's lockstep-negative result. Without
// it the staging loop is structurally identical to the gemm pattern that
// gained 20us in R2.
__device__ __forceinline__ void qk_dual(const u16* Ks, const half8* qfA, const half8* qfB,
                                        floatx4 (&sA)[8], floatx4 (&sB)[8],
                                        int quad, int l16) {
#pragma unroll
  for (int kc = 0; kc < 2; kc++)
#pragma unroll
    for (int st = 0; st < 8; st++) {
      int srow = st * 16 + l16;
      half8 ak = *(const half8*)&Ks[srow * 64 + (((kc * 4 + quad) ^ (srow & 7)) * 8)];
      sA[st] = __builtin_amdgcn_mfma_f32_16x16x32_f16(ak, qfA[kc], sA[st], 0, 0, 0);
      sB[st] = __builtin_amdgcn_mfma_f32_16x16x32_f16(ak, qfB[kc], sB[st], 0, 0, 0);
    }
}
__device__ __forceinline__ void qk_single(const u16* Ks, const half8* qfA,
                                          floatx4 (&sA)[8], int quad, int l16) {
#pragma unroll
  for (int kc = 0; kc < 2; kc++)
#pragma unroll
    for (int st = 0; st < 8; st++) {
      int srow = st * 16 + l16;
      half8 ak = *(const half8*)&Ks[srow * 64 + (((kc * 4 + quad) ^ (srow & 7)) * 8)];
      sA[st] = __builtin_amdgcn_mfma_f32_16x16x32_f16(ak, qfA[kc], sA[st], 0, 0, 0);
    }
}
__device__ __forceinline__ void apply_mask(floatx4 (&s)[8], int kt, int tw, int quad, int l16) {
  int tg = tw + l16;
#pragma unroll
  for (int st = 0; st < 8; st++) {
    int sg = kt * 128 + st * 16 + quad * 4;
#pragma unroll
    for (int r = 0; r < 4; r++)
      if (sg + r > tg) s[st][r] = -1e30f;
  }
}
// online softmax per t-column (base-2; scale folded into q). Defer-max: skip the
// rescale pass while max growth <= 8 (P <= 2^8, fine in f16; lrow/oacc consistent).
__device__ __forceinline__ void softmax_update(floatx4 (&s)[8], float& mrow, float& lrow,
                                               floatx4 (&oacc)[4]) {
  floatx4 vm = s[0];
#pragma unroll
  for (int st = 1; st < 8; st++) {
    vm[0] = fmaxf(vm[0], s[st][0]); vm[1] = fmaxf(vm[1], s[st][1]);
    vm[2] = fmaxf(vm[2], s[st][2]); vm[3] = fmaxf(vm[3], s[st][3]);
  }
  float mx = fmaxf(fmaxf(vm[0], vm[1]), fmaxf(vm[2], vm[3]));
  mx = fmaxf(mx, __shfl_xor(mx, 16));
  mx = fmaxf(mx, __shfl_xor(mx, 32));
  if (!__all(mx <= mrow + 8.f)) {           // rescale needed (also first tile)
    float mnew = fmaxf(mrow, mx);
    float alpha = exp2f(mrow - mnew);
    mrow = mnew;
    lrow *= alpha;
#pragma unroll
    for (int dt = 0; dt < 4; dt++) oacc[dt] *= alpha;
  }
  floatx4 vs = {0.f, 0.f, 0.f, 0.f};
#pragma unroll
  for (int st = 0; st < 8; st++) {
#pragma unroll
    for (int r = 0; r < 4; r++) s[st][r] = exp2f(s[st][r] - mrow);
    vs += s[st];
  }
  float rs = (vs[0] + vs[1]) + (vs[2] + vs[3]);
  rs += __shfl_xor(rs, 16);
  rs += __shfl_xor(rs, 32);
  lrow += rs;
}
// O^T += V^T · P^T : P^T B-frags straight from sacc registers (packed cvt).
// Dual form shares every av read between the two strips.
__device__ __forceinline__ void pv_dual(const u16* Vts, const floatx4 (&sA)[8],
                                        const floatx4 (&sB)[8], floatx4 (&oA)[4],
                                        floatx4 (&oB)[4], int qh2, int ql2, int l16) {
#pragma unroll
  for (int st = 0; st < 8; st++) {
    union { unsigned u[2]; half4 h; } pa, pb;
    pa.u[0] = pk2h(sA[st][0], sA[st][1]); pa.u[1] = pk2h(sA[st][2], sA[st][3]);
    pb.u[0] = pk2h(sB[st][0], sB[st][1]); pb.u[1] = pk2h(sB[st][2], sB[st][3]);
#pragma unroll
    for (int dt = 0; dt < 4; dt++) {
      int drow = dt * 16 + l16;
      half4 av = *(const half4*)&Vts[drow * 128 + (((st * 2 + qh2) ^ (drow & 15)) * 8) + ql2];
      oA[dt] = __builtin_amdgcn_mfma_f32_16x16x16f16(av, pa.h, oA[dt], 0, 0, 0);
      oB[dt] = __builtin_amdgcn_mfma_f32_16x16x16f16(av, pb.h, oB[dt], 0, 0, 0);
    }
  }
}
__device__ __forceinline__ void pv_single(const u16* Vts, const floatx4 (&sA)[8],
                                          floatx4 (&oA)[4], int qh2, int ql2, int l16) {
#pragma unroll
  for (int st = 0; st < 8; st++) {
    union { unsigned u[2]; half4 h; } pa;
    pa.u[0] = pk2h(sA[st][0], sA[st][1]); pa.u[1] = pk2h(sA[st][2], sA[st][3]);
#pragma unroll
    for (int dt = 0; dt < 4; dt++) {
      int drow = dt * 16 + l16;
      half4 av = *(const half4*)&Vts[drow * 128 + (((st * 2 + qh2) ^ (drow & 15)) * 8) + ql2];
      oA[dt] = __builtin_amdgcn_mfma_f32_16x16x16f16(av, pa.h, oA[dt], 0, 0, 0);
    }
  }
}
__device__ __forceinline__ void epilogue(u16* __restrict__ Ob, const floatx4 (&oacc)[4],
                                         float lrow, int b, int h, int tw, int quad, int l16) {
  int t = tw + l16;
  float invl = 1.f / lrow;
#pragma unroll
  for (int dt = 0; dt < 4; dt++) {
    int d0 = dt * 16 + quad * 4;
    ushort4 o;
    o.x = f2bf(oacc[dt][0] * invl);
    o.y = f2bf(oacc[dt][1] * invl);
    o.z = f2bf(oacc[dt][2] * invl);
    o.w = f2bf(oacc[dt][3] * invl);
    *(ushort4*)&Ob[((size_t)(b * T_SEQ) + t) * CDIM + h * HD + d0] = o;
  }
}

__global__ __launch_bounds__(256, 2) void attn_fused(const u16* __restrict__ qf16,
                                                     const u16* __restrict__ kf16,
                                                     const u16* __restrict__ vtf,
                                                     u16* __restrict__ Ob) {
  __shared__ u16 Ks[2][128 * 64];           // K tile (s,d) f16, chunk-swizzled, dbuf
  __shared__ u16 Vts[2][64 * 128];          // V^T tile (d,s) f16, chunk-swizzled, dbuf
  const int tid = threadIdx.x;
  const int lane = tid & 63, wave = tid >> 6;
  const int quad = lane >> 4, l16 = lane & 15;
  const int qh2 = quad >> 1, ql2 = (quad & 1) * 4;
  const int j   = blockIdx.x >> 5;          // pair index 0..15
  const int bh  = blockIdx.x & 31;
  const int b = bh >> 4, h = bh & 15;

  const int qtA = 31 - j, qtB = j;          // heavy / light strip
  const int twA = qtA * 64 + wave * 16;     // this wave's 16 t-columns, strip A
  const int twB = qtB * 64 + wave * 16;
  const int nktA = (qtA >> 1) + 1;          // 9..16 (holds A's diagonal)
  const int nktB = (qtB >> 1) + 1;          // 1..8  (strict prefix of A's range)

  // Q B-frags (16x16x32 layout) straight from global: t=tw+l16, d=kc*32+quad*8+j8
  const u16* QgA = qf16 + ((size_t)bh * T_SEQ + twA) * HD;
  const u16* QgB = qf16 + ((size_t)bh * T_SEQ + twB) * HD;
  half8 qfA[2], qfB[2];
#pragma unroll
  for (int kc = 0; kc < 2; kc++) {
    qfA[kc] = *(const half8*)&QgA[(size_t)l16 * HD + kc * 32 + quad * 8];
    qfB[kc] = *(const half8*)&QgB[(size_t)l16 * HD + kc * 32 + quad * 8];
  }

  auto stage = [&](int buf, int kt) {
    const size_t koff = ((size_t)bh * T_SEQ + kt * 128) * HD;
    const u16* Vg = vtf + (size_t)bh * HD * T_SEQ + kt * 128;
    u16* Kd = &Ks[buf][0];
    u16* Vd = &Vts[buf][0];
#pragma unroll
    for (int jj = 0; jj < 4; jj++) {
      int t2 = jj * 256 + tid;
      int r = t2 >> 3, c = t2 & 7;
      gld16(kf16 + koff + r * HD + (c ^ (r & 7)) * 8, Kd + t2 * 8);
    }
#pragma unroll
    for (int jj = 0; jj < 4; jj++) {
      int t2 = jj * 256 + tid;
      int r = t2 >> 4, c = t2 & 15;
      gld16(Vg + (size_t)r * T_SEQ + (c ^ (r & 15)) * 8, Vd + t2 * 8);
    }
  };

  floatx4 oaccA[4] = {}, oaccB[4] = {};     // O^T tiles [dt]
  float mA = -1e30f, lA = 0.f;
  float mB = -1e30f, lB = 0.f;

  stage(0, 0);                              // prologue: tile 0 in flight
#pragma unroll 1
  for (int kt = 0; kt < nktA; kt++) {
    const int cur = kt & 1;
    __builtin_amdgcn_s_barrier();           // all waves done reading buf cur^1
    int ktn = kt + 1 < nktA ? kt + 1 : nktA - 1;  // clamp: last iter re-stages
    stage(cur ^ 1, ktn);
    asm volatile("s_waitcnt vmcnt(8)" ::: "memory");  // tile kt landed; 8 in flight
    __builtin_amdgcn_s_barrier();           // whole tile kt visible to all waves
    const u16* Kc = &Ks[cur][0];
    const u16* Vc = &Vts[cur][0];

    if (kt < nktB) {
      // dual phase: both strips consume the staged tile; two independent
      // QK->SM->PV chains for MFMA||VALU overlap, shared ak/av LDS reads.
      floatx4 sA[8] = {}, sB[8] = {};
      qk_dual(Kc, qfA, qfB, sA, sB, quad, l16);
      if (kt == nktB - 1) apply_mask(sB, kt, twB, quad, l16);
      softmax_update(sA, mA, lA, oaccA);
      softmax_update(sB, mB, lB, oaccB);
      pv_dual(Vc, sA, sB, oaccA, oaccB, qh2, ql2, l16);
    } else {
      floatx4 sA[8] = {};
      qk_single(Kc, qfA, sA, quad, l16);
      if (kt == nktA - 1) apply_mask(sA, kt, twA, quad, l16);
      softmax_update(sA, mA, lA, oaccA);
      pv_single(Vc, sA, oaccA, qh2, ql2, l16);
    }
  }
  asm volatile("s_waitcnt vmcnt(0)" ::: "memory");  // drain tail stage before exit
  // epilogue: O[t][d] = oacc^T / l ; write bf16 (B,T,C)
  epilogue(Ob, oaccA, lA, b, h, twA, quad, l16);
  epilogue(Ob, oaccB, lB, b, h, twB, quad, l16);
}

extern "C" void kernel_launch(void* const* d_in, const int* in_sizes, int n_in,
                              void* d_out, int out_size, void* d_ws, size_t ws_size,
                              hipStream_t stream) {
  const float* x     = (const float*)d_in[0];
  const float* w_qkv = (const float*)d_in[2];
  const float* w_out = (const float*)d_in[3];
  float* out    = (float*)d_out;                       // (B,T,C) fp32
  float* kt_out = out + (size_t)BDIM * T_SEQ * CDIM;   // (B,H,T,64) fp32
  float* vt_out = kt_out + (size_t)BDIM * T_SEQ * CDIM;

  // workspace layout (64 MB, with aliasing)
  const size_t F = (size_t)4194304;     // 4M elems = 4096x1024
  char* base = (char*)d_ws;
  u16* xb   = (u16*)base;                        // [0,8M)   dead after gemm_qkv
  u16* wqT  = xb + F;                            // [8,14M)  dead after gemm_qkv
  u16* woT  = wqT + (size_t)3145728;             // [14,16M) lives to end
  u16* qkvb = woT + (size_t)1048576;             // [16,40M) dead after rope_vpack
  u16* qf16 = qkvb + (size_t)3 * F;              // [40,48M)
  u16* kf16 = qf16 + F;                          // [48,56M)
  u16* vtf  = (u16*)base;                        // alias xb  [0,8M)
  u16* Ob   = kf16 + F;                          // [56,64M)

  preproc<<<8192, 256, 0, stream>>>(x, w_qkv, w_out, xb, wqT, woT);
  gemm_bt<false><<<dim3(32, 24), 256, 0, stream>>>(xb, wqT, (float*)nullptr, qkvb, 4096, 3072, 1024);
  rope_vpack<<<17408, 256, 0, stream>>>(qkvb, qf16, kf16, kt_out, vt_out, vtf);
  attn_fused<<<512, 256, 0, stream>>>(qf16, kf16, vtf, Ob);
  gemm_bt<true><<<dim3(32, 8), 256, 0, stream>>>(Ob, woT, out, (u16*)nullptr, 4096, 1024, 1024);
}

// Round 4
// 208.269 us; speedup vs baseline: 1.0609x; 1.0047x over previous
//
#include <hip/hip_runtime.h>

// Problem constants (B=2, T=2048, C=1024, H=16, hd=64)
#define T_SEQ 2048
#define NH    16
#define HD    64
#define CDIM  1024
#define BDIM  2

using floatx4 = __attribute__((ext_vector_type(4))) float;
using bf16x8  = __attribute__((ext_vector_type(8))) __bf16;
using half4   = __attribute__((ext_vector_type(4))) _Float16;
using half8   = __attribute__((ext_vector_type(8))) _Float16;
typedef unsigned short u16;

__device__ __forceinline__ u16 f2bf(float f) {
  unsigned int u = __float_as_uint(f);
  u += 0x7fffu + ((u >> 16) & 1u);          // RNE
  return (u16)(u >> 16);
}
__device__ __forceinline__ float bf2f(u16 h) {
  return __uint_as_float(((unsigned int)h) << 16);
}
__device__ __forceinline__ u16 f2h(float f) {
  union { _Float16 h; u16 u; } c; c.h = (_Float16)f; return c.u;
}
// packed f32x2 -> f16x2 (RTZ)
__device__ __forceinline__ unsigned pk2h(float a, float b) {
  return __builtin_bit_cast(unsigned, __builtin_amdgcn_cvt_pkrtz(a, b));
}
// async global->LDS, 16B/lane; LDS dest must be wave-uniform base + lane*16.
__device__ __forceinline__ void gld16(const void* g, const void* l) {
  __builtin_amdgcn_global_load_lds(
      (const __attribute__((address_space(1))) unsigned int*)(unsigned long long)g,
      (__attribute__((address_space(3))) unsigned int*)(unsigned int)(unsigned long long)l,
      16, 0, 0);
}

// ---------------- fused preprocessing: x cast + both weight transposes ----------------
__global__ __launch_bounds__(256) void preproc(const float* __restrict__ x,
                                               const float* __restrict__ w_qkv,
                                               const float* __restrict__ w_out,
                                               u16* __restrict__ xb,
                                               u16* __restrict__ wqT,
                                               u16* __restrict__ woT) {
  __shared__ float tile[32][33];
  int blk = blockIdx.x, tid = threadIdx.x;
  if (blk < 4096) {                         // cast x -> bf16 (4M floats, float4 per thread)
    int i = blk * 256 + tid;
    float4 v = ((const float4*)x)[i];
    ushort4 o;
    o.x = f2bf(v.x); o.y = f2bf(v.y); o.z = f2bf(v.z); o.w = f2bf(v.w);
    ((ushort4*)xb)[i] = o;
    return;
  }
  const float* W; u16* WT; int K, N, bx, by;
  if (blk < 4096 + 3072) {                  // w_qkv (1024,3072) -> wqT (3072,1024)
    int idx = blk - 4096; W = w_qkv; WT = wqT; K = 1024; N = 3072;
    bx = idx % 96; by = idx / 96;
  } else {                                  // w_out (1024,1024) -> woT
    int idx = blk - 7168; W = w_out; WT = woT; K = 1024; N = 1024;
    bx = idx & 31; by = idx >> 5;
  }
  int n0 = bx * 32, k0 = by * 32;
  int tx = tid & 31, ty = tid >> 5;         // (32,8)
#pragma unroll
  for (int i = 0; i < 32; i += 8)
    tile[ty + i][tx] = W[(size_t)(k0 + ty + i) * N + n0 + tx];
  __syncthreads();
#pragma unroll
  for (int i = 0; i < 32; i += 8)
    WT[(size_t)(n0 + ty + i) * K + k0 + tx] = f2bf(tile[tx][ty + i]);
}

// ---------------- single-bf16 GEMM: C(M,N) = A(M,K)*BT(N,K)^T ----------
// 2-phase double-buffered LDS with COUNTED vmcnt (T3/T4 minimum form): stage
// tile ki+1 into buf^1 while MFMAs consume buf, wait vmcnt(4) (next tile's 4
// loads stay in flight across the barrier), raw s_barrier (no lgkm/vm drain).
// Proven +20us total in R2 (gemm_out at 1 block/CU had zero implicit overlap).
template <bool OUT_F32>
__global__ __launch_bounds__(256) void gemm_bt(const u16* __restrict__ A,
                                               const u16* __restrict__ BT,
                                               float* __restrict__ Cf,
                                               u16* __restrict__ Cb,
                                               int M, int N, int K) {
  __shared__ u16 As[2][128 * 32];
  __shared__ u16 Bs[2][128 * 32];
  const int tid  = threadIdx.x;
  const int lane = tid & 63, wave = tid >> 6;
  const int quad = lane >> 4, l16 = lane & 15;
  const int wm = (wave & 1) * 64, wn = (wave >> 1) * 64;
  const int row0 = blockIdx.x * 128, col0 = blockIdx.y * 128;
  const int srow = tid >> 2;                       // staging row 0..63
  const int sc   = tid & 3;                        // chunk 0..3 (8 elems)
  const int sgc  = (sc ^ ((srow >> 1) & 3)) * 8;   // swizzled source chunk
  floatx4 acc[4][4] = {};

  auto stage = [&](int buf, int k0) {
    gld16(A  + (size_t)(row0 + srow     ) * K + k0 + sgc, &As[buf][srow * 32 + sc * 8]);
    gld16(A  + (size_t)(row0 + srow + 64) * K + k0 + sgc, &As[buf][(srow + 64) * 32 + sc * 8]);
    gld16(BT + (size_t)(col0 + srow     ) * K + k0 + sgc, &Bs[buf][srow * 32 + sc * 8]);
    gld16(BT + (size_t)(col0 + srow + 64) * K + k0 + sgc, &Bs[buf][(srow + 64) * 32 + sc * 8]);
  };

  const int nk = K >> 5;
  stage(0, 0);
  for (int ki = 0; ki < nk; ki++) {
    const int cur = ki & 1;
    __builtin_amdgcn_s_barrier();           // all waves done reading buf cur^1
    int kn = ki + 1 < nk ? ki + 1 : nk - 1; // clamp: last iter re-stages (harmless)
    stage(cur ^ 1, kn << 5);
    asm volatile("s_waitcnt vmcnt(4)" ::: "memory");  // tile ki landed; 4 in flight
    __builtin_amdgcn_s_barrier();           // whole tile ki visible to all waves
    bf16x8 af[4], bfv[4];
#pragma unroll
    for (int mt = 0; mt < 4; mt++) {
      int r = wm + mt * 16 + l16;
      af[mt] = *(const bf16x8*)&As[cur][r * 32 + (quad ^ ((r >> 1) & 3)) * 8];
    }
#pragma unroll
    for (int nt = 0; nt < 4; nt++) {
      int r = wn + nt * 16 + l16;
      bfv[nt] = *(const bf16x8*)&Bs[cur][r * 32 + (quad ^ ((r >> 1) & 3)) * 8];
    }
#pragma unroll
    for (int mt = 0; mt < 4; mt++)
#pragma unroll
      for (int nt = 0; nt < 4; nt++)
        acc[mt][nt] = __builtin_amdgcn_mfma_f32_16x16x32_bf16(af[mt], bfv[nt], acc[mt][nt], 0, 0, 0);
  }
  asm volatile("s_waitcnt vmcnt(0)" ::: "memory");  // drain tail stage before exit
  // C/D layout: col = lane&15, row = quad*4 + reg
#pragma unroll
  for (int mt = 0; mt < 4; mt++)
#pragma unroll
    for (int nt = 0; nt < 4; nt++)
#pragma unroll
      for (int r = 0; r < 4; r++) {
        int row = row0 + wm + mt * 16 + quad * 4 + r;
        int col = col0 + wn + nt * 16 + l16;
        float v = acc[mt][nt][r];
        if (OUT_F32) Cf[(size_t)row * N + col] = v;
        else         Cb[(size_t)row * N + col] = f2bf(v);
      }
}

// ---------------- fused RoPE (q,k) + V pack ----------------
__global__ __launch_bounds__(256) void rope_vpack(const u16* __restrict__ qkv,
                                                  u16* __restrict__ qf16,
                                                  u16* __restrict__ kf16,
                                                  float* __restrict__ kt_out,
                                                  float* __restrict__ vt_out,
                                                  u16* __restrict__ vtf) {
  int blk = blockIdx.x;
  if (blk < 16384) {                        // RoPE on q,k
    int gid = blk * 4 + (threadIdx.x >> 6); // (b,h,t) row index
    int d   = threadIdx.x & 63;
    int t   = gid & (T_SEQ - 1);
    int h   = (gid >> 11) & 15;
    int b   = gid >> 15;
    const u16* qrow = qkv + ((size_t)(b * T_SEQ + t)) * 3072 + h * 64;
    int i = d & 31;
    unsigned int qp = *(const unsigned int*)(qrow + 2 * i);
    unsigned int kp = *(const unsigned int*)(qrow + 1024 + 2 * i);
    float q1 = bf2f((u16)qp), q2 = bf2f((u16)(qp >> 16));
    float k1 = bf2f((u16)kp), k2 = bf2f((u16)(kp >> 16));
    float inv = expf((float)i * -0.28782313662425572f);  // 10000^(-i/32)
    float ang = (float)t * inv;
    float sn = sinf(ang), cs = cosf(ang);
    float qv = (d < 32) ? (q1 * cs - q2 * sn) : (q1 * sn + q2 * cs);
    float kv = (d < 32) ? (k1 * cs - k2 * sn) : (k1 * sn + k2 * cs);
    size_t o = (size_t)gid * 64 + d;
    qf16[o] = f2h(qv * 0.18033688011112042f);   // 0.125 * log2(e): base-2 softmax
    kf16[o] = f2h(kv);
    kt_out[o] = kv;
    return;
  }
  // V: v_t fp32 output + V^T f16 (BH,64,T)
  __shared__ float tile[64][65];
  int b2 = blk - 16384;
  int t0 = (b2 & 31) * 64;
  int bh = b2 >> 5;
  int b = bh >> 4, h = bh & 15;
  int tx = threadIdx.x & 63, ty = threadIdx.x >> 6;
#pragma unroll
  for (int i = ty; i < 64; i += 4) {
    float v = bf2f(qkv[((size_t)(b * T_SEQ + t0 + i)) * 3072 + 2048 + h * 64 + tx]);
    tile[i][tx] = v;
    vt_out[((size_t)bh * T_SEQ + t0 + i) * 64 + tx] = v;
  }
  __syncthreads();
#pragma unroll
  for (int i = ty; i < 64; i += 4)
    vtf[((size_t)bh * 64 + i) * T_SEQ + t0 + tx] = f2h(tile[tx][i]);
}

// ---------------- fused causal flash attention, S^T orientation ----------
// DUAL-STREAM PAIRED STRIPS (R1 structure — proven 49.5us; dbuf reverted, it
// cost +5us in R3's A/B). R4: softmax VALU reduction —
//  (a) l-sum moved to the MFMA pipe: one extra mfma_16x16x16f16(ones, P, lsum)
//      per st reuses the P fragment already packed for PV; every lane's
//      lsum[0] is its t-column's running sum (all 16 A-rows identical), so the
//      32 v_add_f32 + 2 cross-lane shuffles per stream/tile vanish. Denominator
//      now sums the SAME f16-rounded P as the numerator.
//  (b) max-reduce written as fmaxf(fmaxf(a,b),c) chains -> v_max3_f32 fusion.
__device__ __forceinline__ void qk_dual(const u16* Ks, const half8* qfA, const half8* qfB,
                                        floatx4 (&sA)[8], floatx4 (&sB)[8],
                                        int quad, int l16) {
#pragma unroll
  for (int kc = 0; kc < 2; kc++)
#pragma unroll
    for (int st = 0; st < 8; st++) {
      int srow = st * 16 + l16;
      half8 ak = *(const half8*)&Ks[srow * 64 + (((kc * 4 + quad) ^ (srow & 7)) * 8)];
      sA[st] = __builtin_amdgcn_mfma_f32_16x16x32_f16(ak, qfA[kc], sA[st], 0, 0, 0);
      sB[st] = __builtin_amdgcn_mfma_f32_16x16x32_f16(ak, qfB[kc], sB[st], 0, 0, 0);
    }
}
__device__ __forceinline__ void qk_single(const u16* Ks, const half8* qfA,
                                          floatx4 (&sA)[8], int quad, int l16) {
#pragma unroll
  for (int kc = 0; kc < 2; kc++)
#pragma unroll
    for (int st = 0; st < 8; st++) {
      int srow = st * 16 + l16;
      half8 ak = *(const half8*)&Ks[srow * 64 + (((kc * 4 + quad) ^ (srow & 7)) * 8)];
      sA[st] = __builtin_amdgcn_mfma_f32_16x16x32_f16(ak, qfA[kc], sA[st], 0, 0, 0);
    }
}
__device__ __forceinline__ void apply_mask(floatx4 (&s)[8], int kt, int tw, int quad, int l16) {
  int tg = tw + l16;
#pragma unroll
  for (int st = 0; st < 8; st++) {
    int sg = kt * 128 + st * 16 + quad * 4;
#pragma unroll
    for (int r = 0; r < 4; r++)
      if (sg + r > tg) s[st][r] = -1e30f;
  }
}
__device__ __forceinline__ float vmax4(const floatx4& v) {
  // fmaxf(fmaxf(a,b),c) chains fuse to v_max3_f32
  return fmaxf(fmaxf(fmaxf(v[0], v[1]), v[2]), v[3]);
}
// online softmax per t-column (base-2; scale folded into q). Defer-max: skip the
// rescale pass while max growth <= 8 (P <= 2^8, fine in f16). l-sum is NOT
// accumulated here anymore — pv_* does it on the MFMA pipe into lsum.
__device__ __forceinline__ void softmax_update(floatx4 (&s)[8], float& mrow,
                                               floatx4& lsum, floatx4 (&oacc)[4]) {
  float p0 = fmaxf(vmax4(s[0]), vmax4(s[1]));
  float p1 = fmaxf(vmax4(s[2]), vmax4(s[3]));
  float p2 = fmaxf(vmax4(s[4]), vmax4(s[5]));
  float p3 = fmaxf(vmax4(s[6]), vmax4(s[7]));
  float mx = fmaxf(fmaxf(fmaxf(p0, p1), p2), p3);
  mx = fmaxf(mx, __shfl_xor(mx, 16));
  mx = fmaxf(mx, __shfl_xor(mx, 32));
  if (!__all(mx <= mrow + 8.f)) {           // rescale needed (also first tile)
    float mnew = fmaxf(mrow, mx);
    float alpha = exp2f(mrow - mnew);
    mrow = mnew;
    lsum *= alpha;
#pragma unroll
    for (int dt = 0; dt < 4; dt++) oacc[dt] *= alpha;
  }
#pragma unroll
  for (int st = 0; st < 8; st++)
#pragma unroll
    for (int r = 0; r < 4; r++) s[st][r] = exp2f(s[st][r] - mrow);
}
// O^T += V^T · P^T, and lsum += ones · P^T (per-t-column sum on the MFMA pipe).
// P^T B-frags straight from sacc registers (packed cvt); dual form shares every
// av read between the two strips.
__device__ __forceinline__ void pv_dual(const u16* Vts, const floatx4 (&sA)[8],
                                        const floatx4 (&sB)[8], floatx4 (&oA)[4],
                                        floatx4 (&oB)[4], floatx4& lsA, floatx4& lsB,
                                        int qh2, int ql2, int l16) {
  const half4 vones = {(_Float16)1.f, (_Float16)1.f, (_Float16)1.f, (_Float16)1.f};
#pragma unroll
  for (int st = 0; st < 8; st++) {
    union { unsigned u[2]; half4 h; } pa, pb;
    pa.u[0] = pk2h(sA[st][0], sA[st][1]); pa.u[1] = pk2h(sA[st][2], sA[st][3]);
    pb.u[0] = pk2h(sB[st][0], sB[st][1]); pb.u[1] = pk2h(sB[st][2], sB[st][3]);
    lsA = __builtin_amdgcn_mfma_f32_16x16x16f16(vones, pa.h, lsA, 0, 0, 0);
    lsB = __builtin_amdgcn_mfma_f32_16x16x16f16(vones, pb.h, lsB, 0, 0, 0);
#pragma unroll
    for (int dt = 0; dt < 4; dt++) {
      int drow = dt * 16 + l16;
      half4 av = *(const half4*)&Vts[drow * 128 + (((st * 2 + qh2) ^ (drow & 15)) * 8) + ql2];
      oA[dt] = __builtin_amdgcn_mfma_f32_16x16x16f16(av, pa.h, oA[dt], 0, 0, 0);
      oB[dt] = __builtin_amdgcn_mfma_f32_16x16x16f16(av, pb.h, oB[dt], 0, 0, 0);
    }
  }
}
__device__ __forceinline__ void pv_single(const u16* Vts, const floatx4 (&sA)[8],
                                          floatx4 (&oA)[4], floatx4& lsA,
                                          int qh2, int ql2, int l16) {
  const half4 vones = {(_Float16)1.f, (_Float16)1.f, (_Float16)1.f, (_Float16)1.f};
#pragma unroll
  for (int st = 0; st < 8; st++) {
    union { unsigned u[2]; half4 h; } pa;
    pa.u[0] = pk2h(sA[st][0], sA[st][1]); pa.u[1] = pk2h(sA[st][2], sA[st][3]);
    lsA = __builtin_amdgcn_mfma_f32_16x16x16f16(vones, pa.h, lsA, 0, 0, 0);
#pragma unroll
    for (int dt = 0; dt < 4; dt++) {
      int drow = dt * 16 + l16;
      half4 av = *(const half4*)&Vts[drow * 128 + (((st * 2 + qh2) ^ (drow & 15)) * 8) + ql2];
      oA[dt] = __builtin_amdgcn_mfma_f32_16x16x16f16(av, pa.h, oA[dt], 0, 0, 0);
    }
  }
}
__device__ __forceinline__ void epilogue(u16* __restrict__ Ob, const floatx4 (&oacc)[4],
                                         const floatx4& lsum, int b, int h, int tw,
                                         int quad, int l16) {
  int t = tw + l16;
  float invl = 1.f / lsum[0];               // all 4 regs identical (ones-rows)
#pragma unroll
  for (int dt = 0; dt < 4; dt++) {
    int d0 = dt * 16 + quad * 4;
    ushort4 o;
    o.x = f2bf(oacc[dt][0] * invl);
    o.y = f2bf(oacc[dt][1] * invl);
    o.z = f2bf(oacc[dt][2] * invl);
    o.w = f2bf(oacc[dt][3] * invl);
    *(ushort4*)&Ob[((size_t)(b * T_SEQ) + t) * CDIM + h * HD + d0] = o;
  }
}

__global__ __launch_bounds__(256, 2) void attn_fused(const u16* __restrict__ qf16,
                                                     const u16* __restrict__ kf16,
                                                     const u16* __restrict__ vtf,
                                                     u16* __restrict__ Ob) {
  __shared__ u16 Ks[128 * 64];              // K tile (s,d) f16, chunk-swizzled
  __shared__ u16 Vts[64 * 128];             // V^T tile (d,s) f16, chunk-swizzled
  const int tid = threadIdx.x;
  const int lane = tid & 63, wave = tid >> 6;
  const int quad = lane >> 4, l16 = lane & 15;
  const int qh2 = quad >> 1, ql2 = (quad & 1) * 4;
  const int j   = blockIdx.x >> 5;          // pair index 0..15
  const int bh  = blockIdx.x & 31;
  const int b = bh >> 4, h = bh & 15;

  const int qtA = 31 - j, qtB = j;          // heavy / light strip
  const int twA = qtA * 64 + wave * 16;     // this wave's 16 t-columns, strip A
  const int twB = qtB * 64 + wave * 16;
  const int nktA = (qtA >> 1) + 1;          // 9..16 (holds A's diagonal)
  const int nktB = (qtB >> 1) + 1;          // 1..8  (strict prefix of A's range)

  // Q B-frags (16x16x32 layout) straight from global: t=tw+l16, d=kc*32+quad*8+j8
  const u16* QgA = qf16 + ((size_t)bh * T_SEQ + twA) * HD;
  const u16* QgB = qf16 + ((size_t)bh * T_SEQ + twB) * HD;
  half8 qfA[2], qfB[2];
#pragma unroll
  for (int kc = 0; kc < 2; kc++) {
    qfA[kc] = *(const half8*)&QgA[(size_t)l16 * HD + kc * 32 + quad * 8];
    qfB[kc] = *(const half8*)&QgB[(size_t)l16 * HD + kc * 32 + quad * 8];
  }

  floatx4 oaccA[4] = {}, oaccB[4] = {};     // O^T tiles [dt]
  floatx4 lsA = {}, lsB = {};               // l-sum MFMA accumulators
  float mA = -1e30f, mB = -1e30f;

#pragma unroll 1
  for (int kt = 0; kt < nktA; kt++) {
    __syncthreads();                        // prev compute done reading Ks/Vts
    const size_t koff = ((size_t)bh * T_SEQ + kt * 128) * HD;
    const u16* Vg = vtf + (size_t)bh * HD * T_SEQ + kt * 128;
#pragma unroll
    for (int jj = 0; jj < 4; jj++) {
      int t2 = jj * 256 + tid;
      int r = t2 >> 3, c = t2 & 7;
      gld16(kf16 + koff + r * HD + (c ^ (r & 7)) * 8, &Ks[t2 * 8]);
    }
#pragma unroll
    for (int jj = 0; jj < 4; jj++) {
      int t2 = jj * 256 + tid;
      int r = t2 >> 4, c = t2 & 15;
      gld16(Vg + (size_t)r * T_SEQ + (c ^ (r & 15)) * 8, &Vts[t2 * 8]);
    }
    __syncthreads();                        // staging landed

    if (kt < nktB) {
      // dual phase: both strips consume the staged tile; two independent
      // QK->SM->PV chains for MFMA||VALU overlap, shared ak/av LDS reads.
      floatx4 sA[8] = {}, sB[8] = {};
      qk_dual(Ks, qfA, qfB, sA, sB, quad, l16);
      if (kt == nktB - 1) apply_mask(sB, kt, twB, quad, l16);
      softmax_update(sA, mA, lsA, oaccA);
      softmax_update(sB, mB, lsB, oaccB);
      pv_dual(Vts, sA, sB, oaccA, oaccB, lsA, lsB, qh2, ql2, l16);
    } else {
      floatx4 sA[8] = {};
      qk_single(Ks, qfA, sA, quad, l16);
      if (kt == nktA - 1) apply_mask(sA, kt, twA, quad, l16);
      softmax_update(sA, mA, lsA, oaccA);
      pv_single(Vts, sA, oaccA, lsA, qh2, ql2, l16);
    }
  }
  // epilogue: O[t][d] = oacc^T / l ; write bf16 (B,T,C)
  epilogue(Ob, oaccA, lsA, b, h, twA, quad, l16);
  epilogue(Ob, oaccB, lsB, b, h, twB, quad, l16);
}

extern "C" void kernel_launch(void* const* d_in, const int* in_sizes, int n_in,
                              void* d_out, int out_size, void* d_ws, size_t ws_size,
                              hipStream_t stream) {
  const float* x     = (const float*)d_in[0];
  const float* w_qkv = (const float*)d_in[2];
  const float* w_out = (const float*)d_in[3];
  float* out    = (float*)d_out;                       // (B,T,C) fp32
  float* kt_out = out + (size_t)BDIM * T_SEQ * CDIM;   // (B,H,T,64) fp32
  float* vt_out = kt_out + (size_t)BDIM * T_SEQ * CDIM;

  // workspace layout (64 MB, with aliasing)
  const size_t F = (size_t)4194304;     // 4M elems = 4096x1024
  char* base = (char*)d_ws;
  u16* xb   = (u16*)base;                        // [0,8M)   dead after gemm_qkv
  u16* wqT  = xb + F;                            // [8,14M)  dead after gemm_qkv
  u16* woT  = wqT + (size_t)3145728;             // [14,16M) lives to end
  u16* qkvb = woT + (size_t)1048576;             // [16,40M) dead after rope_vpack
  u16* qf16 = qkvb + (size_t)3 * F;              // [40,48M)
  u16* kf16 = qf16 + F;                          // [48,56M)
  u16* vtf  = (u16*)base;                        // alias xb  [0,8M)
  u16* Ob   = kf16 + F;                          // [56,64M)

  preproc<<<8192, 256, 0, stream>>>(x, w_qkv, w_out, xb, wqT, woT);
  gemm_bt<false><<<dim3(32, 24), 256, 0, stream>>>(xb, wqT, (float*)nullptr, qkvb, 4096, 3072, 1024);
  rope_vpack<<<17408, 256, 0, stream>>>(qkvb, qf16, kf16, kt_out, vt_out, vtf);
  attn_fused<<<512, 256, 0, stream>>>(qf16, kf16, vtf, Ob);
  gemm_bt<true><<<dim3(32, 8), 256, 0, stream>>>(Ob, woT, out, (u16*)nullptr, 4096, 1024, 1024);
}